// Round 4
// baseline (98.170 us; speedup 1.0000x reference)
//
#include <hip/hip_runtime.h>
#include <hip/hip_bf16.h>
#include <cstdint>

#define BATCH   16384
#define INDIM   512
#define OUTDIM  128
#define NINT    31
#define BM      64
#define THREADS 512

typedef __attribute__((ext_vector_type(8))) short s8v;   // 8 bf16
typedef __attribute__((ext_vector_type(4))) float f4v;   // MFMA acc

__device__ __forceinline__ short bfs(float f) {
    return (short)__builtin_bit_cast(unsigned short, __float2bfloat16(f));
}
__device__ __forceinline__ unsigned int pk2(float lo, float hi) {
    return (unsigned int)(unsigned short)bfs(lo) |
           ((unsigned int)(unsigned short)bfs(hi) << 16);
}

// XOR swizzle on 8-elem (16B) granularity: breaks the 128B-row-stride bank
// pattern on ds_read_b128; residual 2-way conflict is free (m136).
#define SWZ(r, k) ((k) ^ (((r) & 7) << 3))

// Single fused kernel: 8 waves = 4 row-groups x 2 k-halves.
//   P0: stage leaf^T -> LDS bf16 (swizzled); gamma softmax -> LDS
//   P1: partial logits = x @ W^T (+bias in k-half 0), x and W direct from
//       global, f32->bf16 in regs. W rows >=62 clamp to 61: logit cols 62/63
//       are never read by the tree walk, so garbage there is harmless.
//   combine k-halves -> tree walk (64 lanes) -> coefficients bf16 (swizzled)
//   P3: Out = C @ leaf via MFMA, K=64
__global__ __launch_bounds__(THREADS) void mix_fused(
    const float* __restrict__ x, const float* __restrict__ W,
    const float* __restrict__ bvec, const float* __restrict__ gamma,
    const float* __restrict__ leaf, float* __restrict__ out)
{
    __shared__ __align__(16) float Lgp[2][BM][65];          // partial logits (+1 pad)
    __shared__ __align__(16) unsigned short leafT[OUTDIM][64]; // bf16 [col][node], swizzled
    __shared__ __align__(16) unsigned short cbf[BM][64];    // coeffs bf16, swizzled
    __shared__ float gsh0[NINT], gsh1[NINT];

    const int t    = threadIdx.x;
    const int lane = t & 63;
    const int w    = t >> 6;       // wave 0..7
    const int rg   = w & 3;        // row group: rows 16rg..16rg+15
    const int kh   = w >> 2;       // k half: k in [256kh, 256kh+256)
    const int g    = lane >> 4;    // 8-elem k-slot group
    const int lm   = lane & 15;
    const int row0 = blockIdx.x * BM;

    // ---- P0a: leaf^T -> LDS bf16, transposed + swizzled ----
    for (int f = t; f < 63 * 32; f += THREADS) {             // 63 nodes x 32 float4
        int n  = f >> 5;
        int c4 = f & 31;
        float4 lv = *(const float4*)(leaf + (size_t)n * OUTDIM + c4 * 4);
        int col = c4 * 4;
        leafT[col+0][SWZ(col+0, n)] = (unsigned short)bfs(lv.x);
        leafT[col+1][SWZ(col+1, n)] = (unsigned short)bfs(lv.y);
        leafT[col+2][SWZ(col+2, n)] = (unsigned short)bfs(lv.z);
        leafT[col+3][SWZ(col+3, n)] = (unsigned short)bfs(lv.w);
    }
    if (t < OUTDIM) leafT[t][SWZ(t, 63)] = 0;                // pad node 63
    // ---- P0b: softmax(gamma) ----
    if (t < NINT) {
        float a = gamma[2*t], b = gamma[2*t+1];
        float m = fmaxf(a, b);
        float e0 = __expf(a - m), e1 = __expf(b - m);
        float inv = 1.0f / (e0 + e1);
        gsh0[t] = e0 * inv;
        gsh1[t] = e1 * inv;
    }

    // ---- P1: partial logits; bias folded into k-half 0 accumulator ----
    f4v acc[4];
    #pragma unroll
    for (int c = 0; c < 4; ++c) {
        int col = 16*c + lm;
        float b = (kh == 0 && col < 62) ? bvec[col] : 0.0f;
        acc[c] = (f4v){b, b, b, b};
    }
    const float* xrow = x + (size_t)(row0 + 16*rg + lm) * INDIM + 256*kh;
    const float* wp[4];
    #pragma unroll
    for (int c = 0; c < 4; ++c) {
        int wr = 16*c + lm;
        wp[c] = W + (size_t)(wr < 62 ? wr : 61) * INDIM + 256*kh;  // clamp: cols 62/63 unused
    }
    #pragma unroll
    for (int ks = 0; ks < 8; ++ks) {
        const int k0 = ks * 32 + 8 * g;
        float4 x0 = *(const float4*)(xrow + k0);
        float4 x1 = *(const float4*)(xrow + k0 + 4);
        s8v a;
        a[0] = bfs(x0.x); a[1] = bfs(x0.y); a[2] = bfs(x0.z); a[3] = bfs(x0.w);
        a[4] = bfs(x1.x); a[5] = bfs(x1.y); a[6] = bfs(x1.z); a[7] = bfs(x1.w);
        #pragma unroll
        for (int c = 0; c < 4; ++c) {
            float4 w0 = *(const float4*)(wp[c] + k0);
            float4 w1 = *(const float4*)(wp[c] + k0 + 4);
            s8v b;
            b[0] = bfs(w0.x); b[1] = bfs(w0.y); b[2] = bfs(w0.z); b[3] = bfs(w0.w);
            b[4] = bfs(w1.x); b[5] = bfs(w1.y); b[6] = bfs(w1.z); b[7] = bfs(w1.w);
            acc[c] = __builtin_amdgcn_mfma_f32_16x16x32_bf16(a, b, acc[c], 0, 0, 0);
        }
    }
    // C/D layout (HW-verified): col = lane&15, row = 4*(lane>>4) + reg
    #pragma unroll
    for (int c = 0; c < 4; ++c)
        #pragma unroll
        for (int r = 0; r < 4; ++r)
            Lgp[kh][16*rg + 4*g + r][16*c + lm] = acc[c][r];
    __syncthreads();

    // ---- combine the 2 k-halves (512 threads, 8 cols each) ----
    {
        const int row = t >> 3;
        const int c0  = (t & 7) * 8;
        #pragma unroll
        for (int j = 0; j < 8; ++j)
            Lgp[0][row][c0 + j] += Lgp[1][row][c0 + j];
    }
    __syncthreads();

    // ---- P2: per-row tree walk (64 lanes), incremental bf16 packing ----
    if (t < BM) {
        const int row = t;
        float Pp[63];
        unsigned int cvp[32];
        float sv = 0.0f;
        Pp[0] = 1.0f;
        #pragma unroll
        for (int n = 0; n < NINT; ++n) {
            float l0 = Lgp[0][row][2*n];
            float l1 = Lgp[0][row][2*n + 1];
            float r1 = 1.0f / (1.0f + __expf(l0 - l1));      // softmax pair, overflow-safe
            float base = Pp[n] * gsh0[n];
            Pp[2*n + 1] = base * (1.0f - r1);
            Pp[2*n + 2] = base * r1;
            float cval = Pp[n] * gsh1[n];
            if (n & 1) cvp[n >> 1] = pk2(sv, cval); else sv = cval;
        }
        #pragma unroll
        for (int n = NINT; n < 63; ++n) {
            float cval = Pp[n];
            if (n & 1) cvp[n >> 1] = pk2(sv, cval); else sv = cval;
        }
        cvp[31] = pk2(sv, 0.0f);                             // cv[62], pad node 63 = 0
        #pragma unroll
        for (int j = 0; j < 8; ++j) {
            int p = SWZ(row, 8 * j);
            *(uint4*)&cbf[row][p] =
                make_uint4(cvp[4*j], cvp[4*j+1], cvp[4*j+2], cvp[4*j+3]);
        }
    }
    __syncthreads();

    // ---- P3: Out[64][128] = C @ leaf (K=64); wave w: rows rg, col-tiles 4kh+j ----
    f4v o[4] = {};
    #pragma unroll
    for (int kw = 0; kw < 2; ++kw) {
        const int k0 = kw * 32 + 8 * g;
        s8v a = *(const s8v*)&cbf[16*rg + lm][SWZ(lm, k0)];  // (16rg+lm)&7 == lm&7
        #pragma unroll
        for (int j = 0; j < 4; ++j) {
            const int colr = 16*(4*kh + j) + lm;             // colr&7 == lm&7
            s8v b = *(const s8v*)&leafT[colr][SWZ(lm, k0)];
            o[j] = __builtin_amdgcn_mfma_f32_16x16x32_bf16(a, b, o[j], 0, 0, 0);
        }
    }
    #pragma unroll
    for (int j = 0; j < 4; ++j)
        #pragma unroll
        for (int r = 0; r < 4; ++r)
            out[(size_t)(row0 + 16*rg + 4*g + r) * OUTDIM + 16*(4*kh + j) + lm] = o[j][r];
}

extern "C" void kernel_launch(void* const* d_in, const int* in_sizes, int n_in,
                              void* d_out, int out_size, void* d_ws, size_t ws_size,
                              hipStream_t stream) {
    const float* x     = (const float*)d_in[0];
    const float* W     = (const float*)d_in[1];
    const float* b     = (const float*)d_in[2];
    const float* gamma = (const float*)d_in[3];
    const float* leaf  = (const float*)d_in[4];
    float* out = (float*)d_out;
    hipLaunchKernelGGL(mix_fused, dim3(BATCH / BM), dim3(THREADS), 0, stream,
                       x, W, b, gamma, leaf, out);
}